// Round 4
// baseline (458.174 us; speedup 1.0000x reference)
//
#include <hip/hip_runtime.h>

#define IN_CH 512

typedef _Float16 f16x8 __attribute__((ext_vector_type(8)));
typedef float f32x4 __attribute__((ext_vector_type(4)));

// async global->LDS, 16B per lane. LDS dest is wave-uniform base + lane*16.
__device__ __forceinline__ void gload_lds16(const void* g, void* l) {
    __builtin_amdgcn_global_load_lds(
        (const __attribute__((address_space(1))) unsigned int*)g,
        (__attribute__((address_space(3))) unsigned int*)l, 16, 0, 0);
}

// ---------------- degree count (in-degree on col) ----------------
__global__ void k_deg(const int* __restrict__ col, int* __restrict__ deg,
                      int E, int N) {
    int e = blockIdx.x * blockDim.x + threadIdx.x;
    if (e < E) {
        int d = col[e];
        if ((unsigned)d < (unsigned)N) atomicAdd(&deg[d], 1);
    }
}

// ---- single-block scan -> rp; also emits dis = rsqrt(deg+1) and zeroes cursor ----
__global__ __launch_bounds__(1024) void k_scan(const int* __restrict__ deg,
                                               int* __restrict__ rp,
                                               float* __restrict__ dis,
                                               int* __restrict__ cursor, int N) {
    __shared__ int sums[1024];
    int t = threadIdx.x;
    int chunk = (N + 1023) / 1024;
    int start = t * chunk;
    int end = start + chunk; if (end > N) end = N;
    int s = 0;
    for (int i = start; i < end; ++i) s += deg[i];
    sums[t] = s;
    __syncthreads();
    for (int off = 1; off < 1024; off <<= 1) {
        int v = (t >= off) ? sums[t - off] : 0;
        __syncthreads();
        sums[t] += v;
        __syncthreads();
    }
    int run = sums[t] - s;   // exclusive prefix of this chunk
    for (int i = start; i < end; ++i) {
        int d = deg[i];
        rp[i] = run; run += d;
        dis[i] = rsqrtf((float)d + 1.0f);
        cursor[i] = 0;
    }
    if (t == 0) rp[N] = sums[1023];
}

// ---------------- CSR fill (src id + edge norm) ----------------
__global__ void k_fill(const int* __restrict__ ei, const float* __restrict__ dis,
                       const int* __restrict__ rp, int* __restrict__ cursor,
                       int* __restrict__ csrc, float* __restrict__ cnorm,
                       int E, int N) {
    int e = blockIdx.x * blockDim.x + threadIdx.x;
    if (e < E) {
        int s = ei[e];
        int d = ei[E + e];
        if ((unsigned)s < (unsigned)N && (unsigned)d < (unsigned)N) {
            int pos = atomicAdd(&cursor[d], 1);
            int idx = rp[d] + pos;
            csrc[idx] = s;
            cnorm[idx] = dis[s] * dis[d];
        }
    }
}

// ---------------- W1 (512x512 fp32) -> W1t (transposed fp16), LDS tile ----------------
__global__ __launch_bounds__(256) void k_cvt_w(const float* __restrict__ W1,
                                               _Float16* __restrict__ W1t) {
    __shared__ float tile[32][33];
    const int bk = blockIdx.x * 32, bn = blockIdx.y * 32;
    const int tx = threadIdx.x & 31, ty = threadIdx.x >> 5;   // 32 x 8
#pragma unroll
    for (int p = 0; p < 4; ++p)
        tile[ty + p * 8][tx] = W1[(size_t)(bk + ty + p * 8) * 512 + bn + tx];
    __syncthreads();
#pragma unroll
    for (int p = 0; p < 4; ++p)
        W1t[(size_t)(bn + ty + p * 8) * 512 + bk + tx] = (_Float16)tile[tx][ty + p * 8];
}

// ---------------- fp16 MFMA GEMM with fused fp32->fp16 A conversion ----------------
// C[M2,512] = cvt16(A[M2,512] fp32) @ Bt^T.  Block = 256 thr = 4 waves (2x2 of 64x64).
// BK=64. A: reg-staged (2x float4 -> cvt -> ds_write_b128). B: global_load_lds w16.
__global__ __launch_bounds__(256) void k_gemm(const float* __restrict__ A,
                                              const _Float16* __restrict__ Bt,
                                              _Float16* __restrict__ C, int Nrows) {
    __shared__ __align__(16) _Float16 As[128 * 64];
    __shared__ __align__(16) _Float16 Bs[128 * 64];
    const int t = threadIdx.x;
    const int lane = t & 63, w = t >> 6;
    const int wm = w >> 1, wn = w & 1;
    const int bm = blockIdx.x * 128, bn = blockIdx.y * 128;
    const int r = lane & 15, kg = lane >> 4;
    const int lrow = lane >> 3, lcol = (lane & 7) * 8;   // B staging: 8 lanes/row

    // A staging geometry: thread covers rows arow+q*32, cols acol..acol+7 (fp32)
    const int arow = t >> 3, acol = (t & 7) * 8;

    f32x4 acc[4][4];
#pragma unroll
    for (int i = 0; i < 4; ++i)
#pragma unroll
        for (int j = 0; j < 4; ++j) acc[i][j] = (f32x4)0.0f;

    for (int k0 = 0; k0 < 512; k0 += 64) {
        // B tile via async DMA
#pragma unroll
        for (int q = 0; q < 4; ++q) {
            const int row = q * 32 + w * 8 + lrow;
            gload_lds16(Bt + (size_t)(bn + row) * 512 + k0 + lcol,
                        Bs + (q * 256 + w * 64) * 8);
        }
        // A tile via registers with fp32->fp16 convert
#pragma unroll
        for (int q = 0; q < 4; ++q) {
            int grow = bm + q * 32 + arow;
            if (grow >= Nrows) grow = Nrows - 1;   // clamp: x has exactly Nrows rows
            const float* gp = A + (size_t)grow * 512 + k0 + acol;
            float4 u0 = *(const float4*)gp;
            float4 u1 = *(const float4*)(gp + 4);
            f16x8 o;
            o[0] = (_Float16)u0.x; o[1] = (_Float16)u0.y;
            o[2] = (_Float16)u0.z; o[3] = (_Float16)u0.w;
            o[4] = (_Float16)u1.x; o[5] = (_Float16)u1.y;
            o[6] = (_Float16)u1.z; o[7] = (_Float16)u1.w;
            *(f16x8*)(As + ((q * 32 + arow) * 64 + acol)) = o;
        }
        __syncthreads();
#pragma unroll
        for (int kk = 0; kk < 2; ++kk) {
            f16x8 a[4], b[4];
#pragma unroll
            for (int i = 0; i < 4; ++i)
                a[i] = *(const f16x8*)(As + (wm * 64 + i * 16 + r) * 64 + kk * 32 + kg * 8);
#pragma unroll
            for (int j = 0; j < 4; ++j)
                b[j] = *(const f16x8*)(Bs + (wn * 64 + j * 16 + r) * 64 + kk * 32 + kg * 8);
#pragma unroll
            for (int i = 0; i < 4; ++i)
#pragma unroll
                for (int j = 0; j < 4; ++j)
                    acc[i][j] = __builtin_amdgcn_mfma_f32_16x16x32_f16(a[i], b[j], acc[i][j], 0, 0, 0);
        }
        __syncthreads();
    }

    // C/D layout: col = lane&15, row = (lane>>4)*4 + reg
#pragma unroll
    for (int i = 0; i < 4; ++i)
#pragma unroll
        for (int j = 0; j < 4; ++j)
#pragma unroll
            for (int reg = 0; reg < 4; ++reg) {
                int m = bm + wm * 64 + i * 16 + kg * 4 + reg;
                int n = bn + wn * 64 + j * 16 + r;
                C[(size_t)m * 512 + n] = (_Float16)acc[i][j][reg];
            }
}

// ---------------- layer-1 aggregation fused with bias+ReLU+dot(W2) ----------------
// one WAVE per node; each lane owns 8 channels. Unroll 8 for MLP.
__global__ __launch_bounds__(256, 8) void k_agg(const _Float16* __restrict__ xw1,
                                                const float* __restrict__ dis,
                                                const int* __restrict__ rp,
                                                const int* __restrict__ csrc,
                                                const float* __restrict__ cnorm,
                                                const float* __restrict__ b1,
                                                const float* __restrict__ W2,
                                                float* __restrict__ xw2, int N) {
    const int n = blockIdx.x * 4 + (threadIdx.x >> 6);
    if (n >= N) return;
    const int l = threadIdx.x & 63;

    float d = dis[n];
    float dd = d * d;
    f16x8 self = *(const f16x8*)(xw1 + (size_t)n * 512 + l * 8);
    float acc[8];
#pragma unroll
    for (int c = 0; c < 8; ++c) acc[c] = dd * (float)self[c];

    int j = rp[n], jend = rp[n + 1];
    for (; j + 8 <= jend; j += 8) {
        int s[8]; float wt[8]; f16x8 v[8];
#pragma unroll
        for (int u = 0; u < 8; ++u) { s[u] = csrc[j + u]; wt[u] = cnorm[j + u]; }
#pragma unroll
        for (int u = 0; u < 8; ++u)
            v[u] = *(const f16x8*)(xw1 + (size_t)s[u] * 512 + l * 8);
#pragma unroll
        for (int u = 0; u < 8; ++u)
#pragma unroll
            for (int c = 0; c < 8; ++c) acc[c] += wt[u] * (float)v[u][c];
    }
    for (; j + 2 <= jend; j += 2) {
        int s0 = csrc[j], s1 = csrc[j + 1];
        float w0 = cnorm[j], w1 = cnorm[j + 1];
        f16x8 v0 = *(const f16x8*)(xw1 + (size_t)s0 * 512 + l * 8);
        f16x8 v1 = *(const f16x8*)(xw1 + (size_t)s1 * 512 + l * 8);
#pragma unroll
        for (int c = 0; c < 8; ++c) acc[c] += w0 * (float)v0[c] + w1 * (float)v1[c];
    }
    if (j < jend) {
        int s0 = csrc[j];
        float w0 = cnorm[j];
        f16x8 v0 = *(const f16x8*)(xw1 + (size_t)s0 * 512 + l * 8);
#pragma unroll
        for (int c = 0; c < 8; ++c) acc[c] += w0 * (float)v0[c];
    }

    float4 bb0 = *(const float4*)(b1 + l * 8);
    float4 bb1 = *(const float4*)(b1 + l * 8 + 4);
    float4 w20 = *(const float4*)(W2 + l * 8);
    float4 w21 = *(const float4*)(W2 + l * 8 + 4);
    float bbv[8] = {bb0.x, bb0.y, bb0.z, bb0.w, bb1.x, bb1.y, bb1.z, bb1.w};
    float w2v[8] = {w20.x, w20.y, w20.z, w20.w, w21.x, w21.y, w21.z, w21.w};
    float p = 0.0f;
#pragma unroll
    for (int c = 0; c < 8; ++c) {
        float h = fmaxf(acc[c] + bbv[c], 0.0f);
        p += h * w2v[c];
    }
#pragma unroll
    for (int off = 32; off > 0; off >>= 1) p += __shfl_down(p, off);
    if (l == 0) xw2[n] = p;
}

// ---------------- layer-2 aggregation on scalars ----------------
__global__ void k_out(const float* __restrict__ xw2, const float* __restrict__ dis,
                      const int* __restrict__ rp, const int* __restrict__ csrc,
                      const float* __restrict__ cnorm, const float* __restrict__ b2,
                      float* __restrict__ out, int N) {
    int n = blockIdx.x * blockDim.x + threadIdx.x;
    if (n >= N) return;
    float d = dis[n];
    float acc = d * d * xw2[n];
    int j = rp[n], jend = rp[n + 1];
    for (; j + 4 <= jend; j += 4) {
        float a0 = cnorm[j] * xw2[csrc[j]];
        float a1 = cnorm[j + 1] * xw2[csrc[j + 1]];
        float a2 = cnorm[j + 2] * xw2[csrc[j + 2]];
        float a3 = cnorm[j + 3] * xw2[csrc[j + 3]];
        acc += (a0 + a1) + (a2 + a3);
    }
    for (; j < jend; ++j) acc += cnorm[j] * xw2[csrc[j]];
    out[n] = acc + b2[0];
}

extern "C" void kernel_launch(void* const* d_in, const int* in_sizes, int n_in,
                              void* d_out, int out_size, void* d_ws, size_t ws_size,
                              hipStream_t stream) {
    const float* x  = (const float*)d_in[0];
    const int*   ei = (const int*)d_in[1];
    const float* W1 = (const float*)d_in[2];
    const float* b1 = (const float*)d_in[3];
    const float* W2 = (const float*)d_in[4];
    const float* b2 = (const float*)d_in[5];
    float* out = (float*)d_out;

    const int N = in_sizes[0] / IN_CH;            // 50000
    const int E = in_sizes[1] / 2;                // 800000
    const int M2 = ((N + 127) / 128) * 128;       // 50048

    char* ws = (char*)d_ws;
    size_t off = 0;
    auto alloc = [&](size_t bytes) {
        char* p = ws + off;
        off += (bytes + 255) & ~(size_t)255;
        return p;
    };
    _Float16* xw1h = (_Float16*)alloc((size_t)M2 * 512 * sizeof(_Float16)); // 51.25 MB
    _Float16* W1t  = (_Float16*)alloc((size_t)512 * 512 * sizeof(_Float16));
    int*   deg    = (int*)alloc((size_t)N * sizeof(int));
    float* dis    = (float*)alloc((size_t)N * sizeof(float));
    int*   rp     = (int*)alloc((size_t)(N + 1) * sizeof(int));
    int*   cursor = (int*)alloc((size_t)N * sizeof(int));
    int*   csrc   = (int*)alloc((size_t)E * sizeof(int));
    float* cnorm  = (float*)alloc((size_t)E * sizeof(float));
    float* xw2    = (float*)alloc((size_t)N * sizeof(float));

    hipMemsetAsync(deg, 0, (size_t)N * sizeof(int), stream);

    k_deg<<<(E + 255) / 256, 256, 0, stream>>>(ei + E, deg, E, N);
    k_scan<<<1, 1024, 0, stream>>>(deg, rp, dis, cursor, N);
    k_fill<<<(E + 255) / 256, 256, 0, stream>>>(ei, dis, rp, cursor, csrc, cnorm, E, N);
    k_cvt_w<<<dim3(16, 16), 256, 0, stream>>>(W1, W1t);
    k_gemm<<<dim3(M2 / 128, 4), 256, 0, stream>>>(x, W1t, xw1h, N);
    k_agg<<<(N + 3) / 4, 256, 0, stream>>>(xw1h, dis, rp, csrc, cnorm, b1, W2, xw2, N);
    k_out<<<(N + 255) / 256, 256, 0, stream>>>(xw2, dis, rp, csrc, cnorm, b2, out, N);
}

// Round 5
// 413.108 us; speedup vs baseline: 1.1091x; 1.1091x over previous
//
#include <hip/hip_runtime.h>

#define IN_CH 512

typedef _Float16 f16x8 __attribute__((ext_vector_type(8)));
typedef float f32x4 __attribute__((ext_vector_type(4)));

// async global->LDS, 16B per lane. LDS dest is wave-uniform base + lane*16.
__device__ __forceinline__ void gload_lds16(const void* g, void* l) {
    __builtin_amdgcn_global_load_lds(
        (const __attribute__((address_space(1))) unsigned int*)g,
        (__attribute__((address_space(3))) unsigned int*)l, 16, 0, 0);
}

// ---------------- degree count (in-degree on col) ----------------
__global__ void k_deg(const int* __restrict__ col, int* __restrict__ deg,
                      int E, int N) {
    int e = blockIdx.x * blockDim.x + threadIdx.x;
    if (e < E) {
        int d = col[e];
        if ((unsigned)d < (unsigned)N) atomicAdd(&deg[d], 1);
    }
}

// ---- single-block scan -> rp; also emits dis = rsqrt(deg+1) and zeroes cursor ----
__global__ __launch_bounds__(1024) void k_scan(const int* __restrict__ deg,
                                               int* __restrict__ rp,
                                               float* __restrict__ dis,
                                               int* __restrict__ cursor, int N) {
    __shared__ int sums[1024];
    int t = threadIdx.x;
    int chunk = (N + 1023) / 1024;
    int start = t * chunk;
    int end = start + chunk; if (end > N) end = N;
    int s = 0;
    for (int i = start; i < end; ++i) s += deg[i];
    sums[t] = s;
    __syncthreads();
    for (int off = 1; off < 1024; off <<= 1) {
        int v = (t >= off) ? sums[t - off] : 0;
        __syncthreads();
        sums[t] += v;
        __syncthreads();
    }
    int run = sums[t] - s;   // exclusive prefix of this chunk
    for (int i = start; i < end; ++i) {
        int d = deg[i];
        rp[i] = run; run += d;
        dis[i] = rsqrtf((float)d + 1.0f);
        cursor[i] = 0;
    }
    if (t == 0) rp[N] = sums[1023];
}

// ---------------- CSR fill (src id + edge norm) ----------------
__global__ void k_fill(const int* __restrict__ ei, const float* __restrict__ dis,
                       const int* __restrict__ rp, int* __restrict__ cursor,
                       int* __restrict__ csrc, float* __restrict__ cnorm,
                       int E, int N) {
    int e = blockIdx.x * blockDim.x + threadIdx.x;
    if (e < E) {
        int s = ei[e];
        int d = ei[E + e];
        if ((unsigned)s < (unsigned)N && (unsigned)d < (unsigned)N) {
            int pos = atomicAdd(&cursor[d], 1);
            int idx = rp[d] + pos;
            csrc[idx] = s;
            cnorm[idx] = dis[s] * dis[d];
        }
    }
}

// ---------------- fp32 -> fp16 conversion of x, padded to M2 rows ----------------
__global__ void k_cvt_x(const float* __restrict__ x, _Float16* __restrict__ xh,
                        int total, int valid) {
    int i = (blockIdx.x * blockDim.x + threadIdx.x) * 8;
    if (i >= total) return;
    f16x8 o;
    if (i < valid) {
        float4 v0 = *(const float4*)(x + i);
        float4 v1 = *(const float4*)(x + i + 4);
        o[0] = (_Float16)v0.x; o[1] = (_Float16)v0.y;
        o[2] = (_Float16)v0.z; o[3] = (_Float16)v0.w;
        o[4] = (_Float16)v1.x; o[5] = (_Float16)v1.y;
        o[6] = (_Float16)v1.z; o[7] = (_Float16)v1.w;
    } else {
        o = (f16x8)0;
    }
    *(f16x8*)(xh + i) = o;
}

// ---------------- W1 (512x512 fp32) -> W1t (transposed fp16), LDS tile ----------------
__global__ __launch_bounds__(256) void k_cvt_w(const float* __restrict__ W1,
                                               _Float16* __restrict__ W1t) {
    __shared__ float tile[32][33];
    const int bk = blockIdx.x * 32, bn = blockIdx.y * 32;
    const int tx = threadIdx.x & 31, ty = threadIdx.x >> 5;   // 32 x 8
#pragma unroll
    for (int p = 0; p < 4; ++p)
        tile[ty + p * 8][tx] = W1[(size_t)(bk + ty + p * 8) * 512 + bn + tx];
    __syncthreads();
#pragma unroll
    for (int p = 0; p < 4; ++p)
        W1t[(size_t)(bn + ty + p * 8) * 512 + bk + tx] = (_Float16)tile[tx][ty + p * 8];
}

// ---------------- fp16 MFMA GEMM, LDS-staged (m97 structure) ----------------
// C[M2,512] = A[M2,512] @ Bt^T.  Block = 256 thr = 4 waves (2x2 of 64x64).
// BK=64: A tile 128x64 f16 (16KB) + B tile (16KB), global_load_lds width 16.
__global__ __launch_bounds__(256) void k_gemm(const _Float16* __restrict__ A,
                                              const _Float16* __restrict__ Bt,
                                              _Float16* __restrict__ C) {
    __shared__ __align__(16) _Float16 As[128 * 64];
    __shared__ __align__(16) _Float16 Bs[128 * 64];
    const int t = threadIdx.x;
    const int lane = t & 63, w = t >> 6;
    const int wm = w >> 1, wn = w & 1;
    const int bm = blockIdx.x * 128, bn = blockIdx.y * 128;
    const int r = lane & 15, kg = lane >> 4;
    const int lrow = lane >> 3, lcol = (lane & 7) * 8;   // staging: 8 lanes/row

    f32x4 acc[4][4];
#pragma unroll
    for (int i = 0; i < 4; ++i)
#pragma unroll
        for (int j = 0; j < 4; ++j) acc[i][j] = (f32x4)0.0f;

    for (int k0 = 0; k0 < 512; k0 += 64) {
#pragma unroll
        for (int q = 0; q < 4; ++q) {
            const int row = q * 32 + w * 8 + lrow;
            const int ldsbase = (q * 256 + w * 64) * 8;   // elements
            gload_lds16(A + (size_t)(bm + row) * 512 + k0 + lcol, As + ldsbase);
            gload_lds16(Bt + (size_t)(bn + row) * 512 + k0 + lcol, Bs + ldsbase);
        }
        __syncthreads();
#pragma unroll
        for (int kk = 0; kk < 2; ++kk) {
            f16x8 a[4], b[4];
#pragma unroll
            for (int i = 0; i < 4; ++i)
                a[i] = *(const f16x8*)(As + (wm * 64 + i * 16 + r) * 64 + kk * 32 + kg * 8);
#pragma unroll
            for (int j = 0; j < 4; ++j)
                b[j] = *(const f16x8*)(Bs + (wn * 64 + j * 16 + r) * 64 + kk * 32 + kg * 8);
#pragma unroll
            for (int i = 0; i < 4; ++i)
#pragma unroll
                for (int j = 0; j < 4; ++j)
                    acc[i][j] = __builtin_amdgcn_mfma_f32_16x16x32_f16(a[i], b[j], acc[i][j], 0, 0, 0);
        }
        __syncthreads();
    }

    // C/D layout: col = lane&15, row = (lane>>4)*4 + reg
#pragma unroll
    for (int i = 0; i < 4; ++i)
#pragma unroll
        for (int j = 0; j < 4; ++j)
#pragma unroll
            for (int reg = 0; reg < 4; ++reg) {
                int m = bm + wm * 64 + i * 16 + kg * 4 + reg;
                int n = bn + wn * 64 + j * 16 + r;
                C[(size_t)m * 512 + n] = (_Float16)acc[i][j][reg];
            }
}

// ---------------- layer-1 aggregation fused with bias+ReLU+dot(W2) ----------------
// one WAVE per node; each lane owns 8 channels. Unroll 8, NO min-wave bound
// (round-4 lesson: __launch_bounds__(256,8) forced 32 VGPR -> 158 MB scratch spill).
__global__ __launch_bounds__(256) void k_agg(const _Float16* __restrict__ xw1,
                                             const float* __restrict__ dis,
                                             const int* __restrict__ rp,
                                             const int* __restrict__ csrc,
                                             const float* __restrict__ cnorm,
                                             const float* __restrict__ b1,
                                             const float* __restrict__ W2,
                                             float* __restrict__ xw2, int N) {
    const int n = blockIdx.x * 4 + (threadIdx.x >> 6);
    if (n >= N) return;
    const int l = threadIdx.x & 63;

    float d = dis[n];
    float dd = d * d;
    f16x8 self = *(const f16x8*)(xw1 + (size_t)n * 512 + l * 8);
    float acc[8];
#pragma unroll
    for (int c = 0; c < 8; ++c) acc[c] = dd * (float)self[c];

    int j = rp[n], jend = rp[n + 1];
    for (; j + 8 <= jend; j += 8) {
        int s[8]; float wt[8]; f16x8 v[8];
#pragma unroll
        for (int u = 0; u < 8; ++u) { s[u] = csrc[j + u]; wt[u] = cnorm[j + u]; }
#pragma unroll
        for (int u = 0; u < 8; ++u)
            v[u] = *(const f16x8*)(xw1 + (size_t)s[u] * 512 + l * 8);
#pragma unroll
        for (int u = 0; u < 8; ++u)
#pragma unroll
            for (int c = 0; c < 8; ++c) acc[c] += wt[u] * (float)v[u][c];
    }
    for (; j + 2 <= jend; j += 2) {
        int s0 = csrc[j], s1 = csrc[j + 1];
        float w0 = cnorm[j], w1 = cnorm[j + 1];
        f16x8 v0 = *(const f16x8*)(xw1 + (size_t)s0 * 512 + l * 8);
        f16x8 v1 = *(const f16x8*)(xw1 + (size_t)s1 * 512 + l * 8);
#pragma unroll
        for (int c = 0; c < 8; ++c) acc[c] += w0 * (float)v0[c] + w1 * (float)v1[c];
    }
    if (j < jend) {
        int s0 = csrc[j];
        float w0 = cnorm[j];
        f16x8 v0 = *(const f16x8*)(xw1 + (size_t)s0 * 512 + l * 8);
#pragma unroll
        for (int c = 0; c < 8; ++c) acc[c] += w0 * (float)v0[c];
    }

    float4 bb0 = *(const float4*)(b1 + l * 8);
    float4 bb1 = *(const float4*)(b1 + l * 8 + 4);
    float4 w20 = *(const float4*)(W2 + l * 8);
    float4 w21 = *(const float4*)(W2 + l * 8 + 4);
    float bbv[8] = {bb0.x, bb0.y, bb0.z, bb0.w, bb1.x, bb1.y, bb1.z, bb1.w};
    float w2v[8] = {w20.x, w20.y, w20.z, w20.w, w21.x, w21.y, w21.z, w21.w};
    float p = 0.0f;
#pragma unroll
    for (int c = 0; c < 8; ++c) {
        float h = fmaxf(acc[c] + bbv[c], 0.0f);
        p += h * w2v[c];
    }
#pragma unroll
    for (int off = 32; off > 0; off >>= 1) p += __shfl_down(p, off);
    if (l == 0) xw2[n] = p;
}

// ---------------- layer-2 aggregation on scalars ----------------
__global__ void k_out(const float* __restrict__ xw2, const float* __restrict__ dis,
                      const int* __restrict__ rp, const int* __restrict__ csrc,
                      const float* __restrict__ cnorm, const float* __restrict__ b2,
                      float* __restrict__ out, int N) {
    int n = blockIdx.x * blockDim.x + threadIdx.x;
    if (n >= N) return;
    float d = dis[n];
    float acc = d * d * xw2[n];
    int j = rp[n], jend = rp[n + 1];
    for (; j + 4 <= jend; j += 4) {
        float a0 = cnorm[j] * xw2[csrc[j]];
        float a1 = cnorm[j + 1] * xw2[csrc[j + 1]];
        float a2 = cnorm[j + 2] * xw2[csrc[j + 2]];
        float a3 = cnorm[j + 3] * xw2[csrc[j + 3]];
        acc += (a0 + a1) + (a2 + a3);
    }
    for (; j < jend; ++j) acc += cnorm[j] * xw2[csrc[j]];
    out[n] = acc + b2[0];
}

extern "C" void kernel_launch(void* const* d_in, const int* in_sizes, int n_in,
                              void* d_out, int out_size, void* d_ws, size_t ws_size,
                              hipStream_t stream) {
    const float* x  = (const float*)d_in[0];
    const int*   ei = (const int*)d_in[1];
    const float* W1 = (const float*)d_in[2];
    const float* b1 = (const float*)d_in[3];
    const float* W2 = (const float*)d_in[4];
    const float* b2 = (const float*)d_in[5];
    float* out = (float*)d_out;

    const int N = in_sizes[0] / IN_CH;            // 50000
    const int E = in_sizes[1] / 2;                // 800000
    const int M2 = ((N + 127) / 128) * 128;       // 50048

    char* ws = (char*)d_ws;
    size_t off = 0;
    auto alloc = [&](size_t bytes) {
        char* p = ws + off;
        off += (bytes + 255) & ~(size_t)255;
        return p;
    };
    _Float16* xh   = (_Float16*)alloc((size_t)M2 * 512 * sizeof(_Float16)); // 51.25 MB
    _Float16* xw1h = (_Float16*)alloc((size_t)M2 * 512 * sizeof(_Float16)); // 51.25 MB
    _Float16* W1t  = (_Float16*)alloc((size_t)512 * 512 * sizeof(_Float16));
    int*   deg    = (int*)alloc((size_t)N * sizeof(int));
    float* dis    = (float*)alloc((size_t)N * sizeof(float));
    int*   rp     = (int*)alloc((size_t)(N + 1) * sizeof(int));
    int*   cursor = (int*)alloc((size_t)N * sizeof(int));
    int*   csrc   = (int*)alloc((size_t)E * sizeof(int));
    float* cnorm  = (float*)alloc((size_t)E * sizeof(float));
    float* xw2    = (float*)alloc((size_t)N * sizeof(float));

    hipMemsetAsync(deg, 0, (size_t)N * sizeof(int), stream);

    k_deg<<<(E + 255) / 256, 256, 0, stream>>>(ei + E, deg, E, N);
    k_scan<<<1, 1024, 0, stream>>>(deg, rp, dis, cursor, N);
    k_fill<<<(E + 255) / 256, 256, 0, stream>>>(ei, dis, rp, cursor, csrc, cnorm, E, N);

    int total = M2 * 512, valid = N * 512;
    k_cvt_x<<<(total / 8 + 255) / 256, 256, 0, stream>>>(x, xh, total, valid);
    k_cvt_w<<<dim3(16, 16), 256, 0, stream>>>(W1, W1t);
    k_gemm<<<dim3(M2 / 128, 4), 256, 0, stream>>>(xh, W1t, xw1h);
    k_agg<<<(N + 3) / 4, 256, 0, stream>>>(xw1h, dis, rp, csrc, cnorm, b1, W2, xw2, N);
    k_out<<<(N + 255) / 256, 256, 0, stream>>>(xw2, dis, rp, csrc, cnorm, b2, out, N);
}

// Round 6
// 300.851 us; speedup vs baseline: 1.5229x; 1.3731x over previous
//
#include <hip/hip_runtime.h>

#define IN_CH 512
#define SCAN_BLK 1024

typedef _Float16 f16x8 __attribute__((ext_vector_type(8)));
typedef float f32x4 __attribute__((ext_vector_type(4)));

// async global->LDS, 16B per lane. LDS dest is wave-uniform base + lane*16.
__device__ __forceinline__ void gload_lds16(const void* g, void* l) {
    __builtin_amdgcn_global_load_lds(
        (const __attribute__((address_space(1))) unsigned int*)g,
        (__attribute__((address_space(3))) unsigned int*)l, 16, 0, 0);
}

// ---------------- degree count (in-degree on col) ----------------
__global__ void k_deg(const int* __restrict__ col, int* __restrict__ deg,
                      int E, int N) {
    int e = blockIdx.x * blockDim.x + threadIdx.x;
    if (e < E) {
        int d = col[e];
        if ((unsigned)d < (unsigned)N) atomicAdd(&deg[d], 1);
    }
}

// ---------------- parallel scan, pass 1: per-block sums ----------------
__global__ __launch_bounds__(SCAN_BLK) void k_psum(const int* __restrict__ deg,
                                                   int* __restrict__ bsum, int N) {
    __shared__ int red[SCAN_BLK / 64];
    int i = blockIdx.x * SCAN_BLK + threadIdx.x;
    int v = (i < N) ? deg[i] : 0;
#pragma unroll
    for (int off = 32; off > 0; off >>= 1) v += __shfl_down(v, off);
    if ((threadIdx.x & 63) == 0) red[threadIdx.x >> 6] = v;
    __syncthreads();
    if (threadIdx.x == 0) {
        int s = 0;
#pragma unroll
        for (int u = 0; u < SCAN_BLK / 64; ++u) s += red[u];
        bsum[blockIdx.x] = s;
    }
}

// ---------------- parallel scan, pass 2: scan the partials (1 block) ----------------
__global__ __launch_bounds__(SCAN_BLK) void k_pscan(const int* __restrict__ bsum,
                                                    int* __restrict__ boff,
                                                    int* __restrict__ rpN, int nb) {
    __shared__ int sums[SCAN_BLK];
    int t = threadIdx.x;
    int v = (t < nb) ? bsum[t] : 0;
    sums[t] = v;
    __syncthreads();
    for (int off = 1; off < SCAN_BLK; off <<= 1) {
        int u = (t >= off) ? sums[t - off] : 0;
        __syncthreads();
        sums[t] += u;
        __syncthreads();
    }
    if (t < nb) boff[t] = sums[t] - v;      // exclusive
    if (t == 0) *rpN = sums[SCAN_BLK - 1];  // total edge count kept
}

// ---------------- parallel scan, pass 3: per-block scan + write rp/dis/cursor ----------------
__global__ __launch_bounds__(SCAN_BLK) void k_write(const int* __restrict__ deg,
                                                    const int* __restrict__ boff,
                                                    int* __restrict__ rp,
                                                    float* __restrict__ dis,
                                                    int* __restrict__ cursor, int N) {
    __shared__ int sums[SCAN_BLK];
    int t = threadIdx.x;
    int i = blockIdx.x * SCAN_BLK + t;
    int d = (i < N) ? deg[i] : 0;
    sums[t] = d;
    __syncthreads();
    for (int off = 1; off < SCAN_BLK; off <<= 1) {
        int u = (t >= off) ? sums[t - off] : 0;
        __syncthreads();
        sums[t] += u;
        __syncthreads();
    }
    if (i < N) {
        rp[i] = boff[blockIdx.x] + sums[t] - d;   // exclusive prefix
        dis[i] = rsqrtf((float)d + 1.0f);
        cursor[i] = 0;
    }
}

// ---------------- CSR fill (src id + edge norm) ----------------
__global__ void k_fill(const int* __restrict__ ei, const float* __restrict__ dis,
                       const int* __restrict__ rp, int* __restrict__ cursor,
                       int* __restrict__ csrc, float* __restrict__ cnorm,
                       int E, int N) {
    int e = blockIdx.x * blockDim.x + threadIdx.x;
    if (e < E) {
        int s = ei[e];
        int d = ei[E + e];
        if ((unsigned)s < (unsigned)N && (unsigned)d < (unsigned)N) {
            int pos = atomicAdd(&cursor[d], 1);
            int idx = rp[d] + pos;
            csrc[idx] = s;
            cnorm[idx] = dis[s] * dis[d];
        }
    }
}

// ---------------- fp32 -> fp16 conversion of x, padded to M2 rows ----------------
__global__ void k_cvt_x(const float* __restrict__ x, _Float16* __restrict__ xh,
                        int total, int valid) {
    int i = (blockIdx.x * blockDim.x + threadIdx.x) * 8;
    if (i >= total) return;
    f16x8 o;
    if (i < valid) {
        float4 v0 = *(const float4*)(x + i);
        float4 v1 = *(const float4*)(x + i + 4);
        o[0] = (_Float16)v0.x; o[1] = (_Float16)v0.y;
        o[2] = (_Float16)v0.z; o[3] = (_Float16)v0.w;
        o[4] = (_Float16)v1.x; o[5] = (_Float16)v1.y;
        o[6] = (_Float16)v1.z; o[7] = (_Float16)v1.w;
    } else {
        o = (f16x8)0;
    }
    *(f16x8*)(xh + i) = o;
}

// ---------------- W1 (512x512 fp32) -> W1t (transposed fp16), LDS tile ----------------
__global__ __launch_bounds__(256) void k_cvt_w(const float* __restrict__ W1,
                                               _Float16* __restrict__ W1t) {
    __shared__ float tile[32][33];
    const int bk = blockIdx.x * 32, bn = blockIdx.y * 32;
    const int tx = threadIdx.x & 31, ty = threadIdx.x >> 5;   // 32 x 8
#pragma unroll
    for (int p = 0; p < 4; ++p)
        tile[ty + p * 8][tx] = W1[(size_t)(bk + ty + p * 8) * 512 + bn + tx];
    __syncthreads();
#pragma unroll
    for (int p = 0; p < 4; ++p)
        W1t[(size_t)(bn + ty + p * 8) * 512 + bk + tx] = (_Float16)tile[tx][ty + p * 8];
}

// ---------------- fp16 MFMA GEMM, LDS-staged (m97 structure) ----------------
__global__ __launch_bounds__(256) void k_gemm(const _Float16* __restrict__ A,
                                              const _Float16* __restrict__ Bt,
                                              _Float16* __restrict__ C) {
    __shared__ __align__(16) _Float16 As[128 * 64];
    __shared__ __align__(16) _Float16 Bs[128 * 64];
    const int t = threadIdx.x;
    const int lane = t & 63, w = t >> 6;
    const int wm = w >> 1, wn = w & 1;
    const int bm = blockIdx.x * 128, bn = blockIdx.y * 128;
    const int r = lane & 15, kg = lane >> 4;
    const int lrow = lane >> 3, lcol = (lane & 7) * 8;   // staging: 8 lanes/row

    f32x4 acc[4][4];
#pragma unroll
    for (int i = 0; i < 4; ++i)
#pragma unroll
        for (int j = 0; j < 4; ++j) acc[i][j] = (f32x4)0.0f;

    for (int k0 = 0; k0 < 512; k0 += 64) {
#pragma unroll
        for (int q = 0; q < 4; ++q) {
            const int row = q * 32 + w * 8 + lrow;
            const int ldsbase = (q * 256 + w * 64) * 8;   // elements
            gload_lds16(A + (size_t)(bm + row) * 512 + k0 + lcol, As + ldsbase);
            gload_lds16(Bt + (size_t)(bn + row) * 512 + k0 + lcol, Bs + ldsbase);
        }
        __syncthreads();
#pragma unroll
        for (int kk = 0; kk < 2; ++kk) {
            f16x8 a[4], b[4];
#pragma unroll
            for (int i = 0; i < 4; ++i)
                a[i] = *(const f16x8*)(As + (wm * 64 + i * 16 + r) * 64 + kk * 32 + kg * 8);
#pragma unroll
            for (int j = 0; j < 4; ++j)
                b[j] = *(const f16x8*)(Bs + (wn * 64 + j * 16 + r) * 64 + kk * 32 + kg * 8);
#pragma unroll
            for (int i = 0; i < 4; ++i)
#pragma unroll
                for (int j = 0; j < 4; ++j)
                    acc[i][j] = __builtin_amdgcn_mfma_f32_16x16x32_f16(a[i], b[j], acc[i][j], 0, 0, 0);
        }
        __syncthreads();
    }

    // C/D layout: col = lane&15, row = (lane>>4)*4 + reg
#pragma unroll
    for (int i = 0; i < 4; ++i)
#pragma unroll
        for (int j = 0; j < 4; ++j)
#pragma unroll
            for (int reg = 0; reg < 4; ++reg) {
                int m = bm + wm * 64 + i * 16 + kg * 4 + reg;
                int n = bn + wn * 64 + j * 16 + r;
                C[(size_t)m * 512 + n] = (_Float16)acc[i][j][reg];
            }
}

// ---------------- layer-1 aggregation fused with bias+ReLU+dot(W2) ----------------
// one WAVE per node; each lane owns 8 channels. Unroll 8, NO min-wave bound
// (round-4 lesson: __launch_bounds__(256,8) forced 32 VGPR -> 158 MB scratch spill).
__global__ __launch_bounds__(256) void k_agg(const _Float16* __restrict__ xw1,
                                             const float* __restrict__ dis,
                                             const int* __restrict__ rp,
                                             const int* __restrict__ csrc,
                                             const float* __restrict__ cnorm,
                                             const float* __restrict__ b1,
                                             const float* __restrict__ W2,
                                             float* __restrict__ xw2, int N) {
    const int n = blockIdx.x * 4 + (threadIdx.x >> 6);
    if (n >= N) return;
    const int l = threadIdx.x & 63;

    float d = dis[n];
    float dd = d * d;
    f16x8 self = *(const f16x8*)(xw1 + (size_t)n * 512 + l * 8);
    float acc[8];
#pragma unroll
    for (int c = 0; c < 8; ++c) acc[c] = dd * (float)self[c];

    int j = rp[n], jend = rp[n + 1];
    for (; j + 8 <= jend; j += 8) {
        int s[8]; float wt[8]; f16x8 v[8];
#pragma unroll
        for (int u = 0; u < 8; ++u) { s[u] = csrc[j + u]; wt[u] = cnorm[j + u]; }
#pragma unroll
        for (int u = 0; u < 8; ++u)
            v[u] = *(const f16x8*)(xw1 + (size_t)s[u] * 512 + l * 8);
#pragma unroll
        for (int u = 0; u < 8; ++u)
#pragma unroll
            for (int c = 0; c < 8; ++c) acc[c] += wt[u] * (float)v[u][c];
    }
    for (; j + 2 <= jend; j += 2) {
        int s0 = csrc[j], s1 = csrc[j + 1];
        float w0 = cnorm[j], w1 = cnorm[j + 1];
        f16x8 v0 = *(const f16x8*)(xw1 + (size_t)s0 * 512 + l * 8);
        f16x8 v1 = *(const f16x8*)(xw1 + (size_t)s1 * 512 + l * 8);
#pragma unroll
        for (int c = 0; c < 8; ++c) acc[c] += w0 * (float)v0[c] + w1 * (float)v1[c];
    }
    if (j < jend) {
        int s0 = csrc[j];
        float w0 = cnorm[j];
        f16x8 v0 = *(const f16x8*)(xw1 + (size_t)s0 * 512 + l * 8);
#pragma unroll
        for (int c = 0; c < 8; ++c) acc[c] += w0 * (float)v0[c];
    }

    float4 bb0 = *(const float4*)(b1 + l * 8);
    float4 bb1 = *(const float4*)(b1 + l * 8 + 4);
    float4 w20 = *(const float4*)(W2 + l * 8);
    float4 w21 = *(const float4*)(W2 + l * 8 + 4);
    float bbv[8] = {bb0.x, bb0.y, bb0.z, bb0.w, bb1.x, bb1.y, bb1.z, bb1.w};
    float w2v[8] = {w20.x, w20.y, w20.z, w20.w, w21.x, w21.y, w21.z, w21.w};
    float p = 0.0f;
#pragma unroll
    for (int c = 0; c < 8; ++c) {
        float h = fmaxf(acc[c] + bbv[c], 0.0f);
        p += h * w2v[c];
    }
#pragma unroll
    for (int off = 32; off > 0; off >>= 1) p += __shfl_down(p, off);
    if (l == 0) xw2[n] = p;
}

// ---------------- layer-2 aggregation on scalars ----------------
__global__ void k_out(const float* __restrict__ xw2, const float* __restrict__ dis,
                      const int* __restrict__ rp, const int* __restrict__ csrc,
                      const float* __restrict__ cnorm, const float* __restrict__ b2,
                      float* __restrict__ out, int N) {
    int n = blockIdx.x * blockDim.x + threadIdx.x;
    if (n >= N) return;
    float d = dis[n];
    float acc = d * d * xw2[n];
    int j = rp[n], jend = rp[n + 1];
    for (; j + 4 <= jend; j += 4) {
        float a0 = cnorm[j] * xw2[csrc[j]];
        float a1 = cnorm[j + 1] * xw2[csrc[j + 1]];
        float a2 = cnorm[j + 2] * xw2[csrc[j + 2]];
        float a3 = cnorm[j + 3] * xw2[csrc[j + 3]];
        acc += (a0 + a1) + (a2 + a3);
    }
    for (; j < jend; ++j) acc += cnorm[j] * xw2[csrc[j]];
    out[n] = acc + b2[0];
}

extern "C" void kernel_launch(void* const* d_in, const int* in_sizes, int n_in,
                              void* d_out, int out_size, void* d_ws, size_t ws_size,
                              hipStream_t stream) {
    const float* x  = (const float*)d_in[0];
    const int*   ei = (const int*)d_in[1];
    const float* W1 = (const float*)d_in[2];
    const float* b1 = (const float*)d_in[3];
    const float* W2 = (const float*)d_in[4];
    const float* b2 = (const float*)d_in[5];
    float* out = (float*)d_out;

    const int N = in_sizes[0] / IN_CH;            // 50000
    const int E = in_sizes[1] / 2;                // 800000
    const int M2 = ((N + 127) / 128) * 128;       // 50048
    const int NB = (N + SCAN_BLK - 1) / SCAN_BLK; // 49

    char* ws = (char*)d_ws;
    size_t off = 0;
    auto alloc = [&](size_t bytes) {
        char* p = ws + off;
        off += (bytes + 255) & ~(size_t)255;
        return p;
    };
    _Float16* xh   = (_Float16*)alloc((size_t)M2 * 512 * sizeof(_Float16)); // 51.25 MB
    _Float16* xw1h = (_Float16*)alloc((size_t)M2 * 512 * sizeof(_Float16)); // 51.25 MB
    _Float16* W1t  = (_Float16*)alloc((size_t)512 * 512 * sizeof(_Float16));
    int*   deg    = (int*)alloc((size_t)N * sizeof(int));
    float* dis    = (float*)alloc((size_t)N * sizeof(float));
    int*   rp     = (int*)alloc((size_t)(N + 1) * sizeof(int));
    int*   cursor = (int*)alloc((size_t)N * sizeof(int));
    int*   csrc   = (int*)alloc((size_t)E * sizeof(int));
    float* cnorm  = (float*)alloc((size_t)E * sizeof(float));
    float* xw2    = (float*)alloc((size_t)N * sizeof(float));
    int*   bsum   = (int*)alloc((size_t)SCAN_BLK * sizeof(int));
    int*   boff   = (int*)alloc((size_t)SCAN_BLK * sizeof(int));

    hipMemsetAsync(deg, 0, (size_t)N * sizeof(int), stream);

    k_deg<<<(E + 255) / 256, 256, 0, stream>>>(ei + E, deg, E, N);
    k_psum<<<NB, SCAN_BLK, 0, stream>>>(deg, bsum, N);
    k_pscan<<<1, SCAN_BLK, 0, stream>>>(bsum, boff, rp + N, NB);
    k_write<<<NB, SCAN_BLK, 0, stream>>>(deg, boff, rp, dis, cursor, N);
    k_fill<<<(E + 255) / 256, 256, 0, stream>>>(ei, dis, rp, cursor, csrc, cnorm, E, N);

    int total = M2 * 512, valid = N * 512;
    k_cvt_x<<<(total / 8 + 255) / 256, 256, 0, stream>>>(x, xh, total, valid);
    k_cvt_w<<<dim3(16, 16), 256, 0, stream>>>(W1, W1t);
    k_gemm<<<dim3(M2 / 128, 4), 256, 0, stream>>>(xh, W1t, xw1h);
    k_agg<<<(N + 3) / 4, 256, 0, stream>>>(xw1h, dis, rp, csrc, cnorm, b1, W2, xw2, N);
    k_out<<<(N + 255) / 256, 256, 0, stream>>>(xw2, dis, rp, csrc, cnorm, b2, out, N);
}

// Round 7
// 272.934 us; speedup vs baseline: 1.6787x; 1.1023x over previous
//
#include <hip/hip_runtime.h>

#define IN_CH 512
#define SCAN_BLK 1024

typedef _Float16 f16x8 __attribute__((ext_vector_type(8)));
typedef float f32x4 __attribute__((ext_vector_type(4)));

// async global->LDS, 16B per lane. LDS dest is wave-uniform base + lane*16.
__device__ __forceinline__ void gload_lds16(const void* g, void* l) {
    __builtin_amdgcn_global_load_lds(
        (const __attribute__((address_space(1))) unsigned int*)g,
        (__attribute__((address_space(3))) unsigned int*)l, 16, 0, 0);
}

// ---------------- degree count (in-degree on col) ----------------
__global__ void k_deg(const int* __restrict__ col, int* __restrict__ deg,
                      int E, int N) {
    int e = blockIdx.x * blockDim.x + threadIdx.x;
    if (e < E) {
        int d = col[e];
        if ((unsigned)d < (unsigned)N) atomicAdd(&deg[d], 1);
    }
}

// ---------------- scan pass 1: per-block sums ----------------
__global__ __launch_bounds__(SCAN_BLK) void k_psum(const int* __restrict__ deg,
                                                   int* __restrict__ bsum, int N) {
    __shared__ int red[SCAN_BLK / 64];
    int i = blockIdx.x * SCAN_BLK + threadIdx.x;
    int v = (i < N) ? deg[i] : 0;
#pragma unroll
    for (int off = 32; off > 0; off >>= 1) v += __shfl_down(v, off);
    if ((threadIdx.x & 63) == 0) red[threadIdx.x >> 6] = v;
    __syncthreads();
    if (threadIdx.x == 0) {
        int s = 0;
#pragma unroll
        for (int u = 0; u < SCAN_BLK / 64; ++u) s += red[u];
        bsum[blockIdx.x] = s;
    }
}

// ---- scan pass 2: per-block scan + block-offset reduce (gridDim <= 64) ----
// also writes dis = rsqrt(deg+1), zeroes cursor, writes rp[N] = total.
__global__ __launch_bounds__(SCAN_BLK) void k_write(const int* __restrict__ deg,
                                                    const int* __restrict__ bsum,
                                                    int* __restrict__ rp,
                                                    float* __restrict__ dis,
                                                    int* __restrict__ cursor, int N) {
    __shared__ int sums[SCAN_BLK];
    __shared__ int boff_s, tot_s;
    int t = threadIdx.x;
    if (t < 64) {
        int v = (t < (int)gridDim.x) ? bsum[t] : 0;
        int pre = (t < (int)blockIdx.x) ? v : 0;
        int a = pre, b = v;
#pragma unroll
        for (int off = 32; off > 0; off >>= 1) {
            a += __shfl_down(a, off);
            b += __shfl_down(b, off);
        }
        if (t == 0) { boff_s = a; tot_s = b; }
    }
    int i = blockIdx.x * SCAN_BLK + t;
    int d = (i < N) ? deg[i] : 0;
    sums[t] = d;
    __syncthreads();
    for (int off = 1; off < SCAN_BLK; off <<= 1) {
        int u = (t >= off) ? sums[t - off] : 0;
        __syncthreads();
        sums[t] += u;
        __syncthreads();
    }
    if (i < N) {
        rp[i] = boff_s + sums[t] - d;   // exclusive prefix
        dis[i] = rsqrtf((float)d + 1.0f);
        cursor[i] = 0;
    }
    if (blockIdx.x == gridDim.x - 1 && t == 0) rp[N] = tot_s;
}

// ---------------- CSR fill (src id only; norm factored into dis scaling) ----------------
__global__ void k_fill(const int* __restrict__ ei, const int* __restrict__ rp,
                       int* __restrict__ cursor, int* __restrict__ csrc,
                       int E, int N) {
    int e = blockIdx.x * blockDim.x + threadIdx.x;
    if (e < E) {
        int s = ei[e];
        int d = ei[E + e];
        if ((unsigned)s < (unsigned)N && (unsigned)d < (unsigned)N) {
            int pos = atomicAdd(&cursor[d], 1);
            csrc[rp[d] + pos] = s;
        }
    }
}

// ---------------- W1 (512x512 fp32) -> W1t (transposed fp16), LDS tile ----------------
__global__ __launch_bounds__(256) void k_cvt_w(const float* __restrict__ W1,
                                               _Float16* __restrict__ W1t) {
    __shared__ float tile[32][33];
    const int bk = blockIdx.x * 32, bn = blockIdx.y * 32;
    const int tx = threadIdx.x & 31, ty = threadIdx.x >> 5;   // 32 x 8
#pragma unroll
    for (int p = 0; p < 4; ++p)
        tile[ty + p * 8][tx] = W1[(size_t)(bk + ty + p * 8) * 512 + bn + tx];
    __syncthreads();
#pragma unroll
    for (int p = 0; p < 4; ++p)
        W1t[(size_t)(bn + ty + p * 8) * 512 + bk + tx] = (_Float16)tile[tx][ty + p * 8];
}

// ---------------- fused fp16 MFMA GEMM: y[m] = dis[m] * (cvt16(x[m]) @ W1) ----------------
// A: fp32, converted in reg-staging. B: fp16 W1t via global_load_lds.
// 1-D grid, bn-fast + bijective XCD-chunked swizzle: the 4 bn-blocks sharing an
// A-tile run consecutively on the SAME XCD -> A read once per L2 (round-6 lesson:
// (391,4) grid re-fetched A 4x through the ~3.5 TB/s L2-miss path).
__global__ __launch_bounds__(256) void k_gemm(const float* __restrict__ A,
                                              const _Float16* __restrict__ Bt,
                                              const float* __restrict__ dis,
                                              _Float16* __restrict__ C,
                                              int Nrows, int nbm) {
    __shared__ __align__(16) _Float16 As[128 * 64];
    __shared__ __align__(16) _Float16 Bs[128 * 64];
    const int t = threadIdx.x;
    const int lane = t & 63, w = t >> 6;
    const int wm = w >> 1, wn = w & 1;

    const int nwg = nbm * 4;
    const int q = nwg >> 3, r = nwg & 7;
    const int xcd = blockIdx.x & 7, within = blockIdx.x >> 3;
    const int wg = (xcd < r ? xcd * (q + 1) : r * (q + 1) + (xcd - r) * q) + within;
    const int bm = (wg >> 2) * 128, bn = (wg & 3) * 128;

    const int rr = lane & 15, kg = lane >> 4;
    const int lrow = lane >> 3, lcol = (lane & 7) * 8;   // B staging: 8 lanes/row
    const int arow = t >> 3, acol = (t & 7) * 8;         // A staging: fp32->fp16

    f32x4 acc[4][4];
#pragma unroll
    for (int i = 0; i < 4; ++i)
#pragma unroll
        for (int j = 0; j < 4; ++j) acc[i][j] = (f32x4)0.0f;

    for (int k0 = 0; k0 < 512; k0 += 64) {
        // B tile via async DMA
#pragma unroll
        for (int p = 0; p < 4; ++p) {
            const int row = p * 32 + w * 8 + lrow;
            gload_lds16(Bt + (size_t)(bn + row) * 512 + k0 + lcol,
                        Bs + (p * 32 + w * 8) * 64);
        }
        // A tile via registers with fp32->fp16 convert
#pragma unroll
        for (int p = 0; p < 4; ++p) {
            int grow = bm + p * 32 + arow;
            if (grow >= Nrows) grow = Nrows - 1;
            const float* gp = A + (size_t)grow * 512 + k0 + acol;
            float4 u0 = *(const float4*)gp;
            float4 u1 = *(const float4*)(gp + 4);
            f16x8 o;
            o[0] = (_Float16)u0.x; o[1] = (_Float16)u0.y;
            o[2] = (_Float16)u0.z; o[3] = (_Float16)u0.w;
            o[4] = (_Float16)u1.x; o[5] = (_Float16)u1.y;
            o[6] = (_Float16)u1.z; o[7] = (_Float16)u1.w;
            *(f16x8*)(As + ((p * 32 + arow) * 64 + acol)) = o;
        }
        __syncthreads();
#pragma unroll
        for (int kk = 0; kk < 2; ++kk) {
            f16x8 a[4], b[4];
#pragma unroll
            for (int i = 0; i < 4; ++i)
                a[i] = *(const f16x8*)(As + (wm * 64 + i * 16 + rr) * 64 + kk * 32 + kg * 8);
#pragma unroll
            for (int j = 0; j < 4; ++j)
                b[j] = *(const f16x8*)(Bs + (wn * 64 + j * 16 + rr) * 64 + kk * 32 + kg * 8);
#pragma unroll
            for (int i = 0; i < 4; ++i)
#pragma unroll
                for (int j = 0; j < 4; ++j)
                    acc[i][j] = __builtin_amdgcn_mfma_f32_16x16x32_f16(a[i], b[j], acc[i][j], 0, 0, 0);
        }
        __syncthreads();
    }

    // C/D layout: col = lane&15, row = (lane>>4)*4 + reg. Scale row by dis[m].
#pragma unroll
    for (int i = 0; i < 4; ++i)
#pragma unroll
        for (int reg = 0; reg < 4; ++reg) {
            int m = bm + wm * 64 + i * 16 + kg * 4 + reg;
            int mc = (m < Nrows) ? m : Nrows - 1;
            float dm = dis[mc];
#pragma unroll
            for (int j = 0; j < 4; ++j) {
                int n = bn + wn * 64 + j * 16 + rr;
                C[(size_t)m * 512 + n] = (_Float16)(acc[i][j][reg] * dm);
            }
        }
}

// ---------------- layer-1 aggregation fused with bias+ReLU+dot(W2) ----------------
// y = dis*xw1 (prescaled); agg = dis[n] * (y[n] + sum y[src]); z[n] = dis[n]*(relu(agg+b1).W2)
// one WAVE per node; each lane owns 8 channels. Unroll 8, NO min-wave bound
// (round-4 lesson: forcing 32 VGPR -> 158 MB scratch spill).
__global__ __launch_bounds__(256) void k_agg(const _Float16* __restrict__ y,
                                             const float* __restrict__ dis,
                                             const int* __restrict__ rp,
                                             const int* __restrict__ csrc,
                                             const float* __restrict__ b1,
                                             const float* __restrict__ W2,
                                             float* __restrict__ z, int N) {
    const int n = blockIdx.x * 4 + (threadIdx.x >> 6);
    if (n >= N) return;
    const int l = threadIdx.x & 63;

    const float d1 = dis[n];
    f16x8 self = *(const f16x8*)(y + (size_t)n * 512 + l * 8);
    float acc[8];
#pragma unroll
    for (int c = 0; c < 8; ++c) acc[c] = (float)self[c];

    int j = rp[n], jend = rp[n + 1];
    for (; j + 8 <= jend; j += 8) {
        int s[8]; f16x8 v[8];
#pragma unroll
        for (int u = 0; u < 8; ++u) s[u] = csrc[j + u];
#pragma unroll
        for (int u = 0; u < 8; ++u)
            v[u] = *(const f16x8*)(y + (size_t)s[u] * 512 + l * 8);
#pragma unroll
        for (int u = 0; u < 8; ++u)
#pragma unroll
            for (int c = 0; c < 8; ++c) acc[c] += (float)v[u][c];
    }
    for (; j + 2 <= jend; j += 2) {
        int s0 = csrc[j], s1 = csrc[j + 1];
        f16x8 v0 = *(const f16x8*)(y + (size_t)s0 * 512 + l * 8);
        f16x8 v1 = *(const f16x8*)(y + (size_t)s1 * 512 + l * 8);
#pragma unroll
        for (int c = 0; c < 8; ++c) acc[c] += (float)v0[c] + (float)v1[c];
    }
    if (j < jend) {
        f16x8 v0 = *(const f16x8*)(y + (size_t)csrc[j] * 512 + l * 8);
#pragma unroll
        for (int c = 0; c < 8; ++c) acc[c] += (float)v0[c];
    }

    float4 bb0 = *(const float4*)(b1 + l * 8);
    float4 bb1 = *(const float4*)(b1 + l * 8 + 4);
    float4 w20 = *(const float4*)(W2 + l * 8);
    float4 w21 = *(const float4*)(W2 + l * 8 + 4);
    float bbv[8] = {bb0.x, bb0.y, bb0.z, bb0.w, bb1.x, bb1.y, bb1.z, bb1.w};
    float w2v[8] = {w20.x, w20.y, w20.z, w20.w, w21.x, w21.y, w21.z, w21.w};
    float p = 0.0f;
#pragma unroll
    for (int c = 0; c < 8; ++c) {
        float h = fmaxf(acc[c] * d1 + bbv[c], 0.0f);
        p += h * w2v[c];
    }
#pragma unroll
    for (int off = 32; off > 0; off >>= 1) p += __shfl_down(p, off);
    if (l == 0) z[n] = d1 * p;
}

// ---------------- layer-2 aggregation on prescaled scalars ----------------
__global__ void k_out(const float* __restrict__ z, const float* __restrict__ dis,
                      const int* __restrict__ rp, const int* __restrict__ csrc,
                      const float* __restrict__ b2, float* __restrict__ out, int N) {
    int n = blockIdx.x * blockDim.x + threadIdx.x;
    if (n >= N) return;
    float acc = z[n];
    int j = rp[n], jend = rp[n + 1];
    for (; j + 4 <= jend; j += 4) {
        float a0 = z[csrc[j]];
        float a1 = z[csrc[j + 1]];
        float a2 = z[csrc[j + 2]];
        float a3 = z[csrc[j + 3]];
        acc += (a0 + a1) + (a2 + a3);
    }
    for (; j < jend; ++j) acc += z[csrc[j]];
    out[n] = dis[n] * acc + b2[0];
}

extern "C" void kernel_launch(void* const* d_in, const int* in_sizes, int n_in,
                              void* d_out, int out_size, void* d_ws, size_t ws_size,
                              hipStream_t stream) {
    const float* x  = (const float*)d_in[0];
    const int*   ei = (const int*)d_in[1];
    const float* W1 = (const float*)d_in[2];
    const float* b1 = (const float*)d_in[3];
    const float* W2 = (const float*)d_in[4];
    const float* b2 = (const float*)d_in[5];
    float* out = (float*)d_out;

    const int N = in_sizes[0] / IN_CH;            // 50000
    const int E = in_sizes[1] / 2;                // 800000
    const int nbm = (N + 127) / 128;              // 391
    const int M2 = nbm * 128;                     // 50048
    const int NB = (N + SCAN_BLK - 1) / SCAN_BLK; // 49 (must be <= 64 for k_write)

    char* ws = (char*)d_ws;
    size_t off = 0;
    auto alloc = [&](size_t bytes) {
        char* p = ws + off;
        off += (bytes + 255) & ~(size_t)255;
        return p;
    };
    _Float16* y   = (_Float16*)alloc((size_t)M2 * 512 * sizeof(_Float16)); // 51.25 MB
    _Float16* W1t = (_Float16*)alloc((size_t)512 * 512 * sizeof(_Float16));
    int*   deg    = (int*)alloc((size_t)N * sizeof(int));
    float* dis    = (float*)alloc((size_t)N * sizeof(float));
    int*   rp     = (int*)alloc((size_t)(N + 1) * sizeof(int));
    int*   cursor = (int*)alloc((size_t)N * sizeof(int));
    int*   csrc   = (int*)alloc((size_t)E * sizeof(int));
    float* z      = (float*)alloc((size_t)N * sizeof(float));
    int*   bsum   = (int*)alloc((size_t)64 * sizeof(int));

    hipMemsetAsync(deg, 0, (size_t)N * sizeof(int), stream);

    k_deg<<<(E + 255) / 256, 256, 0, stream>>>(ei + E, deg, E, N);
    k_psum<<<NB, SCAN_BLK, 0, stream>>>(deg, bsum, N);
    k_write<<<NB, SCAN_BLK, 0, stream>>>(deg, bsum, rp, dis, cursor, N);
    k_fill<<<(E + 255) / 256, 256, 0, stream>>>(ei, rp, cursor, csrc, E, N);
    k_cvt_w<<<dim3(16, 16), 256, 0, stream>>>(W1, W1t);
    k_gemm<<<nbm * 4, 256, 0, stream>>>(x, W1t, dis, y, N, nbm);
    k_agg<<<(N + 3) / 4, 256, 0, stream>>>(y, dis, rp, csrc, b1, W2, z, N);
    k_out<<<(N + 255) / 256, 256, 0, stream>>>(z, dis, rp, csrc, b2, out, N);
}

// Round 8
// 265.526 us; speedup vs baseline: 1.7255x; 1.0279x over previous
//
#include <hip/hip_runtime.h>

#define IN_CH 512
#define SCAN_BLK 1024

typedef _Float16 f16x8 __attribute__((ext_vector_type(8)));
typedef float f32x4 __attribute__((ext_vector_type(4)));

// async global->LDS, 16B per lane. LDS dest is wave-uniform base + lane*16.
__device__ __forceinline__ void gload_lds16(const void* g, void* l) {
    __builtin_amdgcn_global_load_lds(
        (const __attribute__((address_space(1))) unsigned int*)g,
        (__attribute__((address_space(3))) unsigned int*)l, 16, 0, 0);
}

// ---------------- scan pass 1: per-block sums ----------------
__global__ __launch_bounds__(SCAN_BLK) void k_psum(const int* __restrict__ deg,
                                                   int* __restrict__ bsum, int N) {
    __shared__ int red[SCAN_BLK / 64];
    int i = blockIdx.x * SCAN_BLK + threadIdx.x;
    int v = (i < N) ? deg[i] : 0;
#pragma unroll
    for (int off = 32; off > 0; off >>= 1) v += __shfl_down(v, off);
    if ((threadIdx.x & 63) == 0) red[threadIdx.x >> 6] = v;
    __syncthreads();
    if (threadIdx.x == 0) {
        int s = 0;
#pragma unroll
        for (int u = 0; u < SCAN_BLK / 64; ++u) s += red[u];
        bsum[blockIdx.x] = s;
    }
}

// ---- scan pass 2: per-block scan + block-offset reduce (gridDim <= 64) ----
// also writes dis = rsqrt(deg+1), zeroes cursor, writes rp[N] = total.
__global__ __launch_bounds__(SCAN_BLK) void k_write(const int* __restrict__ deg,
                                                    const int* __restrict__ bsum,
                                                    int* __restrict__ rp,
                                                    float* __restrict__ dis,
                                                    int* __restrict__ cursor, int N) {
    __shared__ int sums[SCAN_BLK];
    __shared__ int boff_s, tot_s;
    int t = threadIdx.x;
    if (t < 64) {
        int v = (t < (int)gridDim.x) ? bsum[t] : 0;
        int pre = (t < (int)blockIdx.x) ? v : 0;
        int a = pre, b = v;
#pragma unroll
        for (int off = 32; off > 0; off >>= 1) {
            a += __shfl_down(a, off);
            b += __shfl_down(b, off);
        }
        if (t == 0) { boff_s = a; tot_s = b; }
    }
    int i = blockIdx.x * SCAN_BLK + t;
    int d = (i < N) ? deg[i] : 0;
    sums[t] = d;
    __syncthreads();
    for (int off = 1; off < SCAN_BLK; off <<= 1) {
        int u = (t >= off) ? sums[t - off] : 0;
        __syncthreads();
        sums[t] += u;
        __syncthreads();
    }
    if (i < N) {
        rp[i] = boff_s + sums[t] - d;   // exclusive prefix
        dis[i] = rsqrtf((float)d + 1.0f);
        cursor[i] = 0;
    }
    if (blockIdx.x == gridDim.x - 1 && t == 0) rp[N] = tot_s;
}

// ---------------- CSR fill (src id only) ----------------
__global__ void k_fill(const int* __restrict__ ei, const int* __restrict__ rp,
                       int* __restrict__ cursor, int* __restrict__ csrc,
                       int E, int N) {
    int e = blockIdx.x * blockDim.x + threadIdx.x;
    if (e < E) {
        int s = ei[e];
        int d = ei[E + e];
        if ((unsigned)s < (unsigned)N && (unsigned)d < (unsigned)N) {
            int pos = atomicAdd(&cursor[d], 1);
            csrc[rp[d] + pos] = s;
        }
    }
}

// ---------------- W1 (512x512 fp32) -> W1t (transposed fp16), LDS tile ----------------
__global__ __launch_bounds__(256) void k_cvt_w(const float* __restrict__ W1,
                                               _Float16* __restrict__ W1t) {
    __shared__ float tile[32][33];
    const int bk = blockIdx.x * 32, bn = blockIdx.y * 32;
    const int tx = threadIdx.x & 31, ty = threadIdx.x >> 5;   // 32 x 8
#pragma unroll
    for (int p = 0; p < 4; ++p)
        tile[ty + p * 8][tx] = W1[(size_t)(bk + ty + p * 8) * 512 + bn + tx];
    __syncthreads();
#pragma unroll
    for (int p = 0; p < 4; ++p)
        W1t[(size_t)(bn + ty + p * 8) * 512 + bk + tx] = (_Float16)tile[tx][ty + p * 8];
}

// ------- merged kernel: blocks [0,nwg) = fused-cvt MFMA GEMM, rest = degree count -------
// GEMM and the graph chain are independent; single-stream serialization was wasting
// k_deg's ~10-15 us. deg's random atomics (latency-bound, ~no BW) hide under GEMM.
// y is UNSCALED (dis applied in k_agg) so gemm has no dependency on the graph chain.
__global__ __launch_bounds__(256) void k_merged(const float* __restrict__ A,
                                                const _Float16* __restrict__ Bt,
                                                _Float16* __restrict__ C,
                                                int Nrows, int nbm,
                                                const int* __restrict__ col,
                                                int* __restrict__ deg, int E, int N) {
    __shared__ __align__(16) _Float16 As[128 * 64];
    __shared__ __align__(16) _Float16 Bs[128 * 64];
    const int nwg = nbm * 4;

    if ((int)blockIdx.x >= nwg) {
        // ---- degree-count part ----
        int e = ((int)blockIdx.x - nwg) * 256 + threadIdx.x;
        if (e < E) {
            int d = col[e];
            if ((unsigned)d < (unsigned)N) atomicAdd(&deg[d], 1);
        }
        return;
    }

    // ---- GEMM part: y[m] = cvt16(x[m]) @ W1  (bn-fast + bijective XCD swizzle) ----
    const int t = threadIdx.x;
    const int lane = t & 63, w = t >> 6;
    const int wm = w >> 1, wn = w & 1;

    const int q = nwg >> 3, r = nwg & 7;
    const int xcd = blockIdx.x & 7, within = blockIdx.x >> 3;
    const int wg = (xcd < r ? xcd * (q + 1) : r * (q + 1) + (xcd - r) * q) + within;
    const int bm = (wg >> 2) * 128, bn = (wg & 3) * 128;

    const int rr = lane & 15, kg = lane >> 4;
    const int lrow = lane >> 3, lcol = (lane & 7) * 8;   // B staging: 8 lanes/row
    const int arow = t >> 3, acol = (t & 7) * 8;         // A staging: fp32->fp16

    f32x4 acc[4][4];
#pragma unroll
    for (int i = 0; i < 4; ++i)
#pragma unroll
        for (int j = 0; j < 4; ++j) acc[i][j] = (f32x4)0.0f;

    for (int k0 = 0; k0 < 512; k0 += 64) {
        // B tile via async DMA
#pragma unroll
        for (int p = 0; p < 4; ++p) {
            const int row = p * 32 + w * 8 + lrow;
            gload_lds16(Bt + (size_t)(bn + row) * 512 + k0 + lcol,
                        Bs + (p * 32 + w * 8) * 64);
        }
        // A tile via registers with fp32->fp16 convert
#pragma unroll
        for (int p = 0; p < 4; ++p) {
            int grow = bm + p * 32 + arow;
            if (grow >= Nrows) grow = Nrows - 1;
            const float* gp = A + (size_t)grow * 512 + k0 + acol;
            float4 u0 = *(const float4*)gp;
            float4 u1 = *(const float4*)(gp + 4);
            f16x8 o;
            o[0] = (_Float16)u0.x; o[1] = (_Float16)u0.y;
            o[2] = (_Float16)u0.z; o[3] = (_Float16)u0.w;
            o[4] = (_Float16)u1.x; o[5] = (_Float16)u1.y;
            o[6] = (_Float16)u1.z; o[7] = (_Float16)u1.w;
            *(f16x8*)(As + ((p * 32 + arow) * 64 + acol)) = o;
        }
        __syncthreads();
#pragma unroll
        for (int kk = 0; kk < 2; ++kk) {
            f16x8 a[4], b[4];
#pragma unroll
            for (int i = 0; i < 4; ++i)
                a[i] = *(const f16x8*)(As + (wm * 64 + i * 16 + rr) * 64 + kk * 32 + kg * 8);
#pragma unroll
            for (int j = 0; j < 4; ++j)
                b[j] = *(const f16x8*)(Bs + (wn * 64 + j * 16 + rr) * 64 + kk * 32 + kg * 8);
#pragma unroll
            for (int i = 0; i < 4; ++i)
#pragma unroll
                for (int j = 0; j < 4; ++j)
                    acc[i][j] = __builtin_amdgcn_mfma_f32_16x16x32_f16(a[i], b[j], acc[i][j], 0, 0, 0);
        }
        __syncthreads();
    }

    // C/D layout: col = lane&15, row = (lane>>4)*4 + reg
#pragma unroll
    for (int i = 0; i < 4; ++i)
#pragma unroll
        for (int j = 0; j < 4; ++j)
#pragma unroll
            for (int reg = 0; reg < 4; ++reg) {
                int m = bm + wm * 64 + i * 16 + kg * 4 + reg;
                int n = bn + wn * 64 + j * 16 + rr;
                C[(size_t)m * 512 + n] = (_Float16)acc[i][j][reg];
            }
}

// ---------------- layer-1 aggregation fused with bias+ReLU+dot(W2) ----------------
// y unscaled: inner = dis_n*y_n + sum_s dis_s*y_s; h = relu(dis_n*inner + b1);
// z[n] = dis_n*(h . W2). One WAVE per node; lane owns 8 channels; unroll 8.
__global__ __launch_bounds__(256) void k_agg(const _Float16* __restrict__ y,
                                             const float* __restrict__ dis,
                                             const int* __restrict__ rp,
                                             const int* __restrict__ csrc,
                                             const float* __restrict__ b1,
                                             const float* __restrict__ W2,
                                             float* __restrict__ z, int N) {
    const int n = blockIdx.x * 4 + (threadIdx.x >> 6);
    if (n >= N) return;
    const int l = threadIdx.x & 63;

    const float d1 = dis[n];
    f16x8 self = *(const f16x8*)(y + (size_t)n * 512 + l * 8);
    float acc[8];
#pragma unroll
    for (int c = 0; c < 8; ++c) acc[c] = d1 * (float)self[c];

    int j = rp[n], jend = rp[n + 1];
    for (; j + 8 <= jend; j += 8) {
        int s[8]; float wt[8]; f16x8 v[8];
#pragma unroll
        for (int u = 0; u < 8; ++u) s[u] = csrc[j + u];
#pragma unroll
        for (int u = 0; u < 8; ++u) wt[u] = dis[s[u]];
#pragma unroll
        for (int u = 0; u < 8; ++u)
            v[u] = *(const f16x8*)(y + (size_t)s[u] * 512 + l * 8);
#pragma unroll
        for (int u = 0; u < 8; ++u)
#pragma unroll
            for (int c = 0; c < 8; ++c) acc[c] += wt[u] * (float)v[u][c];
    }
    for (; j + 2 <= jend; j += 2) {
        int s0 = csrc[j], s1 = csrc[j + 1];
        float w0 = dis[s0], w1 = dis[s1];
        f16x8 v0 = *(const f16x8*)(y + (size_t)s0 * 512 + l * 8);
        f16x8 v1 = *(const f16x8*)(y + (size_t)s1 * 512 + l * 8);
#pragma unroll
        for (int c = 0; c < 8; ++c) acc[c] += w0 * (float)v0[c] + w1 * (float)v1[c];
    }
    if (j < jend) {
        int s0 = csrc[j];
        float w0 = dis[s0];
        f16x8 v0 = *(const f16x8*)(y + (size_t)s0 * 512 + l * 8);
#pragma unroll
        for (int c = 0; c < 8; ++c) acc[c] += w0 * (float)v0[c];
    }

    float4 bb0 = *(const float4*)(b1 + l * 8);
    float4 bb1 = *(const float4*)(b1 + l * 8 + 4);
    float4 w20 = *(const float4*)(W2 + l * 8);
    float4 w21 = *(const float4*)(W2 + l * 8 + 4);
    float bbv[8] = {bb0.x, bb0.y, bb0.z, bb0.w, bb1.x, bb1.y, bb1.z, bb1.w};
    float w2v[8] = {w20.x, w20.y, w20.z, w20.w, w21.x, w21.y, w21.z, w21.w};
    float p = 0.0f;
#pragma unroll
    for (int c = 0; c < 8; ++c) {
        float h = fmaxf(acc[c] * d1 + bbv[c], 0.0f);
        p += h * w2v[c];
    }
#pragma unroll
    for (int off = 32; off > 0; off >>= 1) p += __shfl_down(p, off);
    if (l == 0) z[n] = d1 * p;
}

// ---------------- layer-2 aggregation on prescaled scalars ----------------
__global__ void k_out(const float* __restrict__ z, const float* __restrict__ dis,
                      const int* __restrict__ rp, const int* __restrict__ csrc,
                      const float* __restrict__ b2, float* __restrict__ out, int N) {
    int n = blockIdx.x * blockDim.x + threadIdx.x;
    if (n >= N) return;
    float acc = z[n];
    int j = rp[n], jend = rp[n + 1];
    for (; j + 4 <= jend; j += 4) {
        float a0 = z[csrc[j]];
        float a1 = z[csrc[j + 1]];
        float a2 = z[csrc[j + 2]];
        float a3 = z[csrc[j + 3]];
        acc += (a0 + a1) + (a2 + a3);
    }
    for (; j < jend; ++j) acc += z[csrc[j]];
    out[n] = dis[n] * acc + b2[0];
}

extern "C" void kernel_launch(void* const* d_in, const int* in_sizes, int n_in,
                              void* d_out, int out_size, void* d_ws, size_t ws_size,
                              hipStream_t stream) {
    const float* x  = (const float*)d_in[0];
    const int*   ei = (const int*)d_in[1];
    const float* W1 = (const float*)d_in[2];
    const float* b1 = (const float*)d_in[3];
    const float* W2 = (const float*)d_in[4];
    const float* b2 = (const float*)d_in[5];
    float* out = (float*)d_out;

    const int N = in_sizes[0] / IN_CH;            // 50000
    const int E = in_sizes[1] / 2;                // 800000
    const int nbm = (N + 127) / 128;              // 391
    const int M2 = nbm * 128;                     // 50048
    const int NB = (N + SCAN_BLK - 1) / SCAN_BLK; // 49 (must be <= 64 for k_write)
    const int DEGB = (E + 255) / 256;             // 3125

    char* ws = (char*)d_ws;
    size_t off = 0;
    auto alloc = [&](size_t bytes) {
        char* p = ws + off;
        off += (bytes + 255) & ~(size_t)255;
        return p;
    };
    _Float16* y   = (_Float16*)alloc((size_t)M2 * 512 * sizeof(_Float16)); // 51.25 MB
    _Float16* W1t = (_Float16*)alloc((size_t)512 * 512 * sizeof(_Float16));
    int*   deg    = (int*)alloc((size_t)N * sizeof(int));
    float* dis    = (float*)alloc((size_t)N * sizeof(float));
    int*   rp     = (int*)alloc((size_t)(N + 1) * sizeof(int));
    int*   cursor = (int*)alloc((size_t)N * sizeof(int));
    int*   csrc   = (int*)alloc((size_t)E * sizeof(int));
    float* z      = (float*)alloc((size_t)N * sizeof(float));
    int*   bsum   = (int*)alloc((size_t)64 * sizeof(int));

    hipMemsetAsync(deg, 0, (size_t)N * sizeof(int), stream);

    k_cvt_w<<<dim3(16, 16), 256, 0, stream>>>(W1, W1t);
    k_merged<<<nbm * 4 + DEGB, 256, 0, stream>>>(x, W1t, y, N, nbm,
                                                 ei + E, deg, E, N);
    k_psum<<<NB, SCAN_BLK, 0, stream>>>(deg, bsum, N);
    k_write<<<NB, SCAN_BLK, 0, stream>>>(deg, bsum, rp, dis, cursor, N);
    k_fill<<<(E + 255) / 256, 256, 0, stream>>>(ei, rp, cursor, csrc, E, N);
    k_agg<<<(N + 3) / 4, 256, 0, stream>>>(y, dis, rp, csrc, b1, W2, z, N);
    k_out<<<(N + 255) / 256, 256, 0, stream>>>(z, dis, rp, csrc, b2, out, N);
}